// Round 17
// baseline (738.935 us; speedup 1.0000x reference)
//
#include <hip/hip_runtime.h>
#include <math.h>

#define NTOK 8192
#define DMODEL 1024
#define DFF 4096
#define NEXP 8
#define TILE 128
#define MAXTILES 136
#define MAXROWS (MAXTILES * TILE)
#define MOE_EPS 1e-9f
#define REG64 8192  // u16 per LDS matrix: 128 rows * 64 cols = 16 KB
#define PGRID 1024  // persistent grid: 4 blocks/CU x 256 CU

typedef unsigned short u16;
typedef __bf16 bf16x8 __attribute__((ext_vector_type(8)));
typedef float f32x4 __attribute__((ext_vector_type(4)));

struct Ctrl {
    int counts[NEXP];
    int fill[NEXP];
    int padded_off[NEXP];
    int n_tiles;
    int tile_expert[MAXTILES];
    int tile_base[MAXTILES];
    int tile_valid[MAXTILES];
    float imp[NEXP];
    float zacc;
};

__device__ __forceinline__ u16 f2bf(float f) {
    unsigned u = __float_as_uint(f);
    unsigned r = u + 0x7fffu + ((u >> 16) & 1u);
    return (u16)(r >> 16);
}

__device__ __forceinline__ void load16(const void* g, void* l) {
    __builtin_amdgcn_global_load_lds((__attribute__((address_space(1))) void*)g,
                                     (__attribute__((address_space(3))) void*)l,
                                     16, 0, 0);
}

// fast GELU: h*sigmoid(1.59577h+0.071355h^3) (tanh-form), |err| < 1e-3
__device__ __forceinline__ float gelu_fast(float h) {
    float u = h * (1.5957691216f + 0.0713548162f * h * h);
    return h / (1.f + __expf(-u));
}

// ---------------- fused fp32 -> bf16 convert (w1 and w2 in one launch) ----------------
__global__ __launch_bounds__(256) void k_convert2(const float* __restrict__ s1,
                                                  u16* __restrict__ d1, int n4a,
                                                  const float* __restrict__ s2,
                                                  u16* __restrict__ d2, int n4tot) {
    int i = blockIdx.x * 256 + threadIdx.x;
    int stride = gridDim.x * 256;
    for (; i < n4tot; i += stride) {
        const float4* src = (i < n4a) ? (const float4*)s1 + i : (const float4*)s2 + (i - n4a);
        ushort4* dst = (i < n4a) ? (ushort4*)d1 + i : (ushort4*)d2 + (i - n4a);
        float4 v = *src;
        ushort4 o;
        o.x = f2bf(v.x); o.y = f2bf(v.y); o.z = f2bf(v.z); o.w = f2bf(v.w);
        *dst = o;
    }
}

// ---------------- router (+ fused x->bf16 conversion) ----------------
__global__ __launch_bounds__(256) void k_router(const float* __restrict__ x,
                                                const float* __restrict__ rw,
                                                u16* __restrict__ xb,
                                                int* __restrict__ top_idx,
                                                float* __restrict__ top_w,
                                                Ctrl* __restrict__ ctrl) {
    __shared__ float srw[NEXP * DMODEL];
    __shared__ float simp[NEXP];
    __shared__ float szl;
    int tid = threadIdx.x;
    for (int i = tid; i < NEXP * DMODEL / 4; i += 256)
        ((float4*)srw)[i] = ((const float4*)rw)[i];
    if (tid < NEXP) simp[tid] = 0.f;
    if (tid == 0) szl = 0.f;
    __syncthreads();

    int lane = tid & 63;
    int n = blockIdx.x * 4 + (tid >> 6);
    float p[NEXP];
#pragma unroll
    for (int e = 0; e < NEXP; ++e) p[e] = 0.f;
    const float4* xr = (const float4*)(x + (size_t)n * DMODEL);
    u16 xs[16];
#pragma unroll
    for (int j = 0; j < 4; ++j) {
        float4 xv = xr[lane * 4 + j];
        int d = (lane * 4 + j) * 4;
        xs[j * 4 + 0] = f2bf(xv.x);
        xs[j * 4 + 1] = f2bf(xv.y);
        xs[j * 4 + 2] = f2bf(xv.z);
        xs[j * 4 + 3] = f2bf(xv.w);
#pragma unroll
        for (int e = 0; e < NEXP; ++e) {
            const float* r = srw + e * DMODEL + d;
            p[e] += xv.x * r[0] + xv.y * r[1] + xv.z * r[2] + xv.w * r[3];
        }
    }
    {
        uint4* dst = (uint4*)(xb + (size_t)n * DMODEL + lane * 16);
        dst[0] = ((const uint4*)xs)[0];
        dst[1] = ((const uint4*)xs)[1];
    }
#pragma unroll
    for (int e = 0; e < NEXP; ++e) {
#pragma unroll
        for (int off = 32; off > 0; off >>= 1) p[e] += __shfl_xor(p[e], off);
    }
    if (lane == 0) {
        float m = p[0];
#pragma unroll
        for (int e = 1; e < NEXP; ++e) m = fmaxf(m, p[e]);
        float pr[NEXP];
        float s = 0.f;
#pragma unroll
        for (int e = 0; e < NEXP; ++e) { pr[e] = expf(p[e] - m); s += pr[e]; }
        float inv = 1.f / s;
#pragma unroll
        for (int e = 0; e < NEXP; ++e) pr[e] *= inv;
        float lse = m + logf(s);
        int i0 = 0; float v0 = pr[0];
#pragma unroll
        for (int e = 1; e < NEXP; ++e) if (pr[e] > v0) { v0 = pr[e]; i0 = e; }
        int i1 = -1; float v1 = -1.f;
#pragma unroll
        for (int e = 0; e < NEXP; ++e) if (e != i0 && pr[e] > v1) { v1 = pr[e]; i1 = e; }
        float den = v0 + v1 + MOE_EPS;
        top_idx[n * 2] = i0;
        top_idx[n * 2 + 1] = i1;
        top_w[n * 2] = v0 / den;
        top_w[n * 2 + 1] = v1 / den;
#pragma unroll
        for (int e = 0; e < NEXP; ++e) atomicAdd(&simp[e], pr[e]);
        atomicAdd(&szl, lse * lse);
    }
    __syncthreads();
    if (tid < NEXP) atomicAdd(&ctrl->imp[tid], simp[tid]);
    if (tid == 255) atomicAdd(&ctrl->zacc, szl);
}

// ---------------- build schedule + finalize aux outputs ----------------
__global__ __launch_bounds__(256) void k_build(const int* __restrict__ top_idx,
                                               Ctrl* __restrict__ ctrl,
                                               int* __restrict__ tok_idx,
                                               float* __restrict__ tok_w,
                                               float* __restrict__ out) {
    __shared__ int cnt[NEXP];
    __shared__ int off[NEXP];
    __shared__ int tiles[NEXP];
    int tid = threadIdx.x;
    if (tid < NEXP) cnt[tid] = 0;
    __syncthreads();
    for (int i = tid; i < NTOK * 2; i += 256) atomicAdd(&cnt[top_idx[i]], 1);
    __syncthreads();
    if (tid == 0) {
        int o = 0, t = 0;
        for (int e = 0; e < NEXP; ++e) {
            int c = cnt[e];
            int te = (c + TILE - 1) / TILE;
            ctrl->counts[e] = c;
            ctrl->padded_off[e] = o;
            off[e] = o;
            tiles[e] = te;
            for (int i = 0; i < te; ++i) {
                ctrl->tile_expert[t] = e;
                ctrl->tile_base[t] = o + i * TILE;
                int v = c - i * TILE;
                ctrl->tile_valid[t] = v > TILE ? TILE : v;
                ++t;
            }
            o += te * TILE;
        }
        ctrl->n_tiles = t;
        // ---- finalize (router's imp/zacc complete; counts just computed) ----
        float imp[NEXP], ld[NEXP];
        float imps = 0.f, loads = 0.f;
        for (int e = 0; e < NEXP; ++e) {
            imp[e] = ctrl->imp[e];
            ld[e] = (float)cnt[e];
            imps += imp[e];
            loads += ld[e];
        }
        float bal = 0.f;
        for (int e = 0; e < NEXP; ++e)
            bal += (imp[e] / (imps + MOE_EPS)) * (ld[e] / (loads + MOE_EPS));
        bal *= (float)NEXP;
        float z = ctrl->zacc / (float)NTOK;
        float aux = 0.01f * bal + 0.001f * z;
        size_t base = (size_t)NTOK * DMODEL;
        out[base] = aux;
        for (int e = 0; e < NEXP; ++e) out[base + 1 + e] = ld[e];
        for (int e = 0; e < NEXP; ++e) out[base + 9 + e] = imp[e];
    }
    __syncthreads();
    for (int e = 0; e < NEXP; ++e) {
        int start = off[e] + cnt[e];
        int end = off[e] + tiles[e] * TILE;
        for (int i = start + tid; i < end; i += 256) {
            tok_idx[i] = 0;
            tok_w[i] = 0.f;
        }
    }
}

// ---------------- fill token lists ----------------
__global__ __launch_bounds__(256) void k_fill(const int* __restrict__ top_idx,
                                              const float* __restrict__ top_w,
                                              Ctrl* __restrict__ ctrl,
                                              int* __restrict__ tok_idx,
                                              float* __restrict__ tok_w) {
    int n = blockIdx.x * 256 + threadIdx.x;
    if (n >= NTOK) return;
#pragma unroll
    for (int k = 0; k < 2; ++k) {
        int e = top_idx[n * 2 + k];
        int pos = atomicAdd(&ctrl->fill[e], 1);
        int slot = ctrl->padded_off[e] + pos;
        tok_idx[slot] = n;
        tok_w[slot] = top_w[n * 2 + k];
    }
}

// ======== 128x128, BK=64, SINGLE-buffer (m97 structure), 32 KB LDS, 4 blocks/CU ========
// (r16 structure, unchanged.)  r13 lesson: (256,4) is the reg-budget ceiling.
// Swizzle: stored chunk s at row holds global chunk s^(row&7); read chunk c ->
// stored c^(l15&7): 2-way bank alias (free, m136).
#define KLOOPM97(STA, STB, NK)                                                        \
    for (int kt = 0; kt < (NK); ++kt) {                                               \
        STA(kt); STB(kt);                                                             \
        asm volatile("s_waitcnt vmcnt(0)" ::: "memory");                              \
        __builtin_amdgcn_s_barrier();                                                 \
        bf16x8 a[4], b[4];                                                            \
        _Pragma("unroll") for (int m = 0; m < 4; ++m) a[m] = *(const bf16x8*)(sA + aoff[m] + csw0); \
        _Pragma("unroll") for (int n = 0; n < 4; ++n) b[n] = *(const bf16x8*)(sB + boff[n] + csw0); \
        __builtin_amdgcn_s_setprio(1);                                                \
        _Pragma("unroll") for (int m = 0; m < 4; ++m)                                 \
            _Pragma("unroll") for (int n = 0; n < 4; ++n)                             \
                acc[m][n] = __builtin_amdgcn_mfma_f32_16x16x32_bf16(a[m], b[n], acc[m][n], 0, 0, 0); \
        __builtin_amdgcn_s_setprio(0);                                                \
        _Pragma("unroll") for (int m = 0; m < 4; ++m) a[m] = *(const bf16x8*)(sA + aoff[m] + csw1); \
        _Pragma("unroll") for (int n = 0; n < 4; ++n) b[n] = *(const bf16x8*)(sB + boff[n] + csw1); \
        __builtin_amdgcn_s_setprio(1);                                                \
        _Pragma("unroll") for (int m = 0; m < 4; ++m)                                 \
            _Pragma("unroll") for (int n = 0; n < 4; ++n)                             \
                acc[m][n] = __builtin_amdgcn_mfma_f32_16x16x32_bf16(a[m], b[n], acc[m][n], 0, 0, 0); \
        __builtin_amdgcn_s_setprio(0);                                                \
        __builtin_amdgcn_s_barrier();                                                 \
    }

// ============ GEMM1: H = gelu(Xg @ w1^T + b1) [persistent 1024 blocks] ============
// work w -> t=(w&7)+8*(w>>8), n0=((w>>3)&31)*128. Stride PGRID keeps n0 and
// XCD (=w&7) invariant per block: A-panel L2 locality preserved; tail rounds
// eliminated (4.25 -> exactly 4-5 tiles/block).
__global__ __launch_bounds__(256, 4) void k_gemm1(const u16* __restrict__ xb,
                                                  const u16* __restrict__ w1b,
                                                  const float* __restrict__ b1,
                                                  const int* __restrict__ tok_idx,
                                                  const Ctrl* __restrict__ ctrl,
                                                  u16* __restrict__ H) {
    __shared__ __align__(16) u16 sA[REG64];
    __shared__ __align__(16) u16 sB[REG64];

    int tid = threadIdx.x;
    int lane = tid & 63, w = tid >> 6;
    int wr = w >> 1, wc = w & 1;               // 2M x 2N waves; wave tile 64x64
    int l15 = lane & 15, lg = lane >> 4;
    int bank7 = l15 & 7;
    int csw0 = ((lg + 0) ^ bank7) * 8;
    int csw1 = ((lg + 4) ^ bank7) * 8;

    int aoff[4], boff[4];
#pragma unroll
    for (int m = 0; m < 4; ++m) aoff[m] = (wr * 64 + m * 16 + l15) * 64;
#pragma unroll
    for (int n = 0; n < 4; ++n) boff[n] = (wc * 64 + n * 16 + l15) * 64;

    int n_tiles = ctrl->n_tiles;
    for (int wk = blockIdx.x; wk < MAXTILES * 32; wk += PGRID) {
        int t = (wk & 7) + ((wk >> 8) << 3);
        int n0 = ((wk >> 3) & 31) * TILE;
        if (t >= n_tiles) continue;
        int e = ctrl->tile_expert[t];
        int rbase = ctrl->tile_base[t];

        const u16* aS[4];
        const u16* bS[4];
        int fo[4];
#pragma unroll
        for (int q = 0; q < 4; ++q) {
            int f = q * 256 + tid;             // 0..1023
            int row = f >> 3;                  // 0..127
            int lc = (f & 7) ^ (row & 7);      // inverse-swizzled source chunk
            aS[q] = xb + (size_t)tok_idx[rbase + row] * DMODEL + lc * 8;
            bS[q] = w1b + (size_t)e * DFF * DMODEL + (size_t)(n0 + row) * DMODEL + lc * 8;
            fo[q] = f * 8;
        }

#define STA1(kt)                                                                      \
    do { _Pragma("unroll") for (int q = 0; q < 4; ++q)                                \
        load16(aS[q] + (kt) * 64, &sA[fo[q]]); } while (0)
#define STB1(kt)                                                                      \
    do { _Pragma("unroll") for (int q = 0; q < 4; ++q)                                \
        load16(bS[q] + (kt) * 64, &sB[fo[q]]); } while (0)

        f32x4 acc[4][4];
#pragma unroll
        for (int m = 0; m < 4; ++m)
#pragma unroll
            for (int n = 0; n < 4; ++n) acc[m][n] = (f32x4){0.f, 0.f, 0.f, 0.f};

        KLOOPM97(STA1, STB1, DMODEL / 64)
#undef STA1
#undef STB1

        float bias[4];
#pragma unroll
        for (int n = 0; n < 4; ++n) bias[n] = b1[e * DFF + n0 + wc * 64 + n * 16 + l15];
#pragma unroll
        for (int m = 0; m < 4; ++m)
#pragma unroll
            for (int n = 0; n < 4; ++n) {
                int gcol = n0 + wc * 64 + n * 16 + l15;
#pragma unroll
                for (int r = 0; r < 4; ++r) {
                    int grow = wr * 64 + m * 16 + lg * 4 + r;
                    float h = acc[m][n][r] + bias[n];
                    H[(size_t)(rbase + grow) * DFF + gcol] = f2bf(gelu_fast(h));
                }
            }
        __builtin_amdgcn_s_barrier();   // all waves done with sA/sB before next tile stages
    }
}

// ============ GEMM2: y += w * (H @ w2^T + b2) [persistent 1024 blocks] ============
// work w -> t=(w&7)+((w>>6)<<3), n0=((w>>3)&7)*128. Stride PGRID: n0, XCD fixed.
__global__ __launch_bounds__(256, 4) void k_gemm2(const u16* __restrict__ H,
                                                  const u16* __restrict__ w2b,
                                                  const float* __restrict__ b2,
                                                  const int* __restrict__ tok_idx,
                                                  const float* __restrict__ tok_w,
                                                  const Ctrl* __restrict__ ctrl,
                                                  float* __restrict__ y) {
    __shared__ __align__(16) u16 sA[REG64];
    __shared__ __align__(16) u16 sB[REG64];

    int tid = threadIdx.x;
    int lane = tid & 63, w = tid >> 6;
    int wr = w >> 1, wc = w & 1;
    int l15 = lane & 15, lg = lane >> 4;
    int bank7 = l15 & 7;
    int csw0 = ((lg + 0) ^ bank7) * 8;
    int csw1 = ((lg + 4) ^ bank7) * 8;

    int aoff[4], boff[4];
#pragma unroll
    for (int m = 0; m < 4; ++m) aoff[m] = (wr * 64 + m * 16 + l15) * 64;
#pragma unroll
    for (int n = 0; n < 4; ++n) boff[n] = (wc * 64 + n * 16 + l15) * 64;

    int n_tiles = ctrl->n_tiles;
    for (int wk = blockIdx.x; wk < MAXTILES * 8; wk += PGRID) {
        int t = (wk & 7) + ((wk >> 6) << 3);
        int n0 = ((wk >> 3) & 7) * TILE;
        if (t >= n_tiles) continue;
        int e = ctrl->tile_expert[t];
        int rbase = ctrl->tile_base[t];
        int valid = ctrl->tile_valid[t];

        const u16* aS[4];
        const u16* bS[4];
        int fo[4];
#pragma unroll
        for (int q = 0; q < 4; ++q) {
            int f = q * 256 + tid;
            int row = f >> 3;
            int lc = (f & 7) ^ (row & 7);
            aS[q] = H + (size_t)(rbase + row) * DFF + lc * 8;
            bS[q] = w2b + (size_t)e * DMODEL * DFF + (size_t)(n0 + row) * DFF + lc * 8;
            fo[q] = f * 8;
        }

#define STA2(kt)                                                                      \
    do { _Pragma("unroll") for (int q = 0; q < 4; ++q)                                \
        load16(aS[q] + (kt) * 64, &sA[fo[q]]); } while (0)
#define STB2(kt)                                                                      \
    do { _Pragma("unroll") for (int q = 0; q < 4; ++q)                                \
        load16(bS[q] + (kt) * 64, &sB[fo[q]]); } while (0)

        f32x4 acc[4][4];
#pragma unroll
        for (int m = 0; m < 4; ++m)
#pragma unroll
            for (int n = 0; n < 4; ++n) acc[m][n] = (f32x4){0.f, 0.f, 0.f, 0.f};

        KLOOPM97(STA2, STB2, DFF / 64)
#undef STA2
#undef STB2

        float bias[4];
#pragma unroll
        for (int n = 0; n < 4; ++n) bias[n] = b2[e * DMODEL + n0 + wc * 64 + n * 16 + l15];
#pragma unroll
        for (int m = 0; m < 4; ++m)
#pragma unroll
            for (int n = 0; n < 4; ++n) {
                int gcol = n0 + wc * 64 + n * 16 + l15;
#pragma unroll
                for (int r = 0; r < 4; ++r) {
                    int grow = wr * 64 + m * 16 + lg * 4 + r;
                    if (grow < valid) {
                        int slot = rbase + grow;
                        int tok = tok_idx[slot];
                        float wgt = tok_w[slot];
                        unsafeAtomicAdd(&y[(size_t)tok * DMODEL + gcol],
                                        wgt * (acc[m][n][r] + bias[n]));
                    }
                }
            }
        __builtin_amdgcn_s_barrier();
    }
}

extern "C" void kernel_launch(void* const* d_in, const int* in_sizes, int n_in,
                              void* d_out, int out_size, void* d_ws, size_t ws_size,
                              hipStream_t stream) {
    (void)in_sizes; (void)n_in; (void)out_size; (void)ws_size;
    const float* x  = (const float*)d_in[0];
    const float* rw = (const float*)d_in[1];
    const float* w1 = (const float*)d_in[2];
    const float* b1 = (const float*)d_in[3];
    const float* w2 = (const float*)d_in[4];
    const float* b2 = (const float*)d_in[5];
    float* out = (float*)d_out;

    char* p = (char*)d_ws;
    Ctrl* ctrl = (Ctrl*)p;          p += 4096;
    u16* xb    = (u16*)p;           p += (size_t)NTOK * DMODEL * 2;
    u16* w1b   = (u16*)p;           p += (size_t)NEXP * DFF * DMODEL * 2;
    u16* w2b   = (u16*)p;           p += (size_t)NEXP * DMODEL * DFF * 2;
    u16* Hbuf  = (u16*)p;           p += (size_t)MAXROWS * DFF * 2;
    int* tok_idx = (int*)p;         p += (size_t)MAXROWS * 4;
    float* tok_w = (float*)p;       p += (size_t)MAXROWS * 4;
    int* tIdx  = (int*)p;           p += (size_t)NTOK * 2 * 4;
    float* tW  = (float*)p;         p += (size_t)NTOK * 2 * 4;

    hipMemsetAsync(ctrl, 0, sizeof(Ctrl), stream);
    hipMemsetAsync(d_out, 0, (size_t)NTOK * DMODEL * sizeof(float), stream);

    int n4a = NEXP * DFF * DMODEL / 4;
    k_convert2<<<2048, 256, 0, stream>>>(w1, w1b, n4a, w2, w2b, 2 * n4a);

    k_router<<<NTOK / 4, 256, 0, stream>>>(x, rw, xb, tIdx, tW, ctrl);
    k_build<<<1, 256, 0, stream>>>(tIdx, ctrl, tok_idx, tok_w, out);
    k_fill<<<NTOK / 256, 256, 0, stream>>>(tIdx, tW, ctrl, tok_idx, tok_w);

    k_gemm1<<<PGRID, 256, 0, stream>>>(xb, w1b, b1, tok_idx, ctrl, Hbuf);
    k_gemm2<<<PGRID, 256, 0, stream>>>(Hbuf, w2b, b2, tok_idx, tok_w, ctrl, out);
}

// Round 18
// 688.035 us; speedup vs baseline: 1.0740x; 1.0740x over previous
//
#include <hip/hip_runtime.h>
#include <math.h>

#define NTOK 8192
#define DMODEL 1024
#define DFF 4096
#define NEXP 8
#define TILE 128
#define MAXTILES 136
#define MAXROWS (MAXTILES * TILE)
#define MOE_EPS 1e-9f
#define REG64 8192  // u16 per LDS matrix: 128 rows * 64 cols = 16 KB

typedef unsigned short u16;
typedef __bf16 bf16x8 __attribute__((ext_vector_type(8)));
typedef float f32x4 __attribute__((ext_vector_type(4)));

struct Ctrl {
    int counts[NEXP];
    int fill[NEXP];
    int padded_off[NEXP];
    int n_tiles;
    int tile_expert[MAXTILES];
    int tile_base[MAXTILES];
    int tile_valid[MAXTILES];
    float imp[NEXP];
    float zacc;
};

__device__ __forceinline__ u16 f2bf(float f) {
    unsigned u = __float_as_uint(f);
    unsigned r = u + 0x7fffu + ((u >> 16) & 1u);
    return (u16)(r >> 16);
}

__device__ __forceinline__ void load16(const void* g, void* l) {
    __builtin_amdgcn_global_load_lds((__attribute__((address_space(1))) void*)g,
                                     (__attribute__((address_space(3))) void*)l,
                                     16, 0, 0);
}

// fast GELU: h*sigmoid(1.59577h+0.071355h^3) (tanh-form), |err| < 1e-3
__device__ __forceinline__ float gelu_fast(float h) {
    float u = h * (1.5957691216f + 0.0713548162f * h * h);
    return h / (1.f + __expf(-u));
}

// ---------------- fused fp32 -> bf16 convert (w1 and w2 in one launch) ----------------
__global__ __launch_bounds__(256) void k_convert2(const float* __restrict__ s1,
                                                  u16* __restrict__ d1, int n4a,
                                                  const float* __restrict__ s2,
                                                  u16* __restrict__ d2, int n4tot) {
    int i = blockIdx.x * 256 + threadIdx.x;
    int stride = gridDim.x * 256;
    for (; i < n4tot; i += stride) {
        const float4* src = (i < n4a) ? (const float4*)s1 + i : (const float4*)s2 + (i - n4a);
        ushort4* dst = (i < n4a) ? (ushort4*)d1 + i : (ushort4*)d2 + (i - n4a);
        float4 v = *src;
        ushort4 o;
        o.x = f2bf(v.x); o.y = f2bf(v.y); o.z = f2bf(v.z); o.w = f2bf(v.w);
        *dst = o;
    }
}

// ---------------- router (+ fused x->bf16 conversion) ----------------
__global__ __launch_bounds__(256) void k_router(const float* __restrict__ x,
                                                const float* __restrict__ rw,
                                                u16* __restrict__ xb,
                                                int* __restrict__ top_idx,
                                                float* __restrict__ top_w,
                                                Ctrl* __restrict__ ctrl) {
    __shared__ float srw[NEXP * DMODEL];
    __shared__ float simp[NEXP];
    __shared__ float szl;
    int tid = threadIdx.x;
    for (int i = tid; i < NEXP * DMODEL / 4; i += 256)
        ((float4*)srw)[i] = ((const float4*)rw)[i];
    if (tid < NEXP) simp[tid] = 0.f;
    if (tid == 0) szl = 0.f;
    __syncthreads();

    int lane = tid & 63;
    int n = blockIdx.x * 4 + (tid >> 6);
    float p[NEXP];
#pragma unroll
    for (int e = 0; e < NEXP; ++e) p[e] = 0.f;
    const float4* xr = (const float4*)(x + (size_t)n * DMODEL);
    u16 xs[16];
#pragma unroll
    for (int j = 0; j < 4; ++j) {
        float4 xv = xr[lane * 4 + j];
        int d = (lane * 4 + j) * 4;
        xs[j * 4 + 0] = f2bf(xv.x);
        xs[j * 4 + 1] = f2bf(xv.y);
        xs[j * 4 + 2] = f2bf(xv.z);
        xs[j * 4 + 3] = f2bf(xv.w);
#pragma unroll
        for (int e = 0; e < NEXP; ++e) {
            const float* r = srw + e * DMODEL + d;
            p[e] += xv.x * r[0] + xv.y * r[1] + xv.z * r[2] + xv.w * r[3];
        }
    }
    {
        uint4* dst = (uint4*)(xb + (size_t)n * DMODEL + lane * 16);
        dst[0] = ((const uint4*)xs)[0];
        dst[1] = ((const uint4*)xs)[1];
    }
#pragma unroll
    for (int e = 0; e < NEXP; ++e) {
#pragma unroll
        for (int off = 32; off > 0; off >>= 1) p[e] += __shfl_xor(p[e], off);
    }
    if (lane == 0) {
        float m = p[0];
#pragma unroll
        for (int e = 1; e < NEXP; ++e) m = fmaxf(m, p[e]);
        float pr[NEXP];
        float s = 0.f;
#pragma unroll
        for (int e = 0; e < NEXP; ++e) { pr[e] = expf(p[e] - m); s += pr[e]; }
        float inv = 1.f / s;
#pragma unroll
        for (int e = 0; e < NEXP; ++e) pr[e] *= inv;
        float lse = m + logf(s);
        int i0 = 0; float v0 = pr[0];
#pragma unroll
        for (int e = 1; e < NEXP; ++e) if (pr[e] > v0) { v0 = pr[e]; i0 = e; }
        int i1 = -1; float v1 = -1.f;
#pragma unroll
        for (int e = 0; e < NEXP; ++e) if (e != i0 && pr[e] > v1) { v1 = pr[e]; i1 = e; }
        float den = v0 + v1 + MOE_EPS;
        top_idx[n * 2] = i0;
        top_idx[n * 2 + 1] = i1;
        top_w[n * 2] = v0 / den;
        top_w[n * 2 + 1] = v1 / den;
#pragma unroll
        for (int e = 0; e < NEXP; ++e) atomicAdd(&simp[e], pr[e]);
        atomicAdd(&szl, lse * lse);
    }
    __syncthreads();
    if (tid < NEXP) atomicAdd(&ctrl->imp[tid], simp[tid]);
    if (tid == 255) atomicAdd(&ctrl->zacc, szl);
}

// ---------------- build schedule + finalize aux outputs ----------------
__global__ __launch_bounds__(256) void k_build(const int* __restrict__ top_idx,
                                               Ctrl* __restrict__ ctrl,
                                               int* __restrict__ tok_idx,
                                               float* __restrict__ tok_w,
                                               float* __restrict__ out) {
    __shared__ int cnt[NEXP];
    __shared__ int off[NEXP];
    __shared__ int tiles[NEXP];
    int tid = threadIdx.x;
    if (tid < NEXP) cnt[tid] = 0;
    __syncthreads();
    for (int i = tid; i < NTOK * 2; i += 256) atomicAdd(&cnt[top_idx[i]], 1);
    __syncthreads();
    if (tid == 0) {
        int o = 0, t = 0;
        for (int e = 0; e < NEXP; ++e) {
            int c = cnt[e];
            int te = (c + TILE - 1) / TILE;
            ctrl->counts[e] = c;
            ctrl->padded_off[e] = o;
            off[e] = o;
            tiles[e] = te;
            for (int i = 0; i < te; ++i) {
                ctrl->tile_expert[t] = e;
                ctrl->tile_base[t] = o + i * TILE;
                int v = c - i * TILE;
                ctrl->tile_valid[t] = v > TILE ? TILE : v;
                ++t;
            }
            o += te * TILE;
        }
        ctrl->n_tiles = t;
        // ---- finalize (router's imp/zacc complete; counts just computed) ----
        float imp[NEXP], ld[NEXP];
        float imps = 0.f, loads = 0.f;
        for (int e = 0; e < NEXP; ++e) {
            imp[e] = ctrl->imp[e];
            ld[e] = (float)cnt[e];
            imps += imp[e];
            loads += ld[e];
        }
        float bal = 0.f;
        for (int e = 0; e < NEXP; ++e)
            bal += (imp[e] / (imps + MOE_EPS)) * (ld[e] / (loads + MOE_EPS));
        bal *= (float)NEXP;
        float z = ctrl->zacc / (float)NTOK;
        float aux = 0.01f * bal + 0.001f * z;
        size_t base = (size_t)NTOK * DMODEL;
        out[base] = aux;
        for (int e = 0; e < NEXP; ++e) out[base + 1 + e] = ld[e];
        for (int e = 0; e < NEXP; ++e) out[base + 9 + e] = imp[e];
    }
    __syncthreads();
    for (int e = 0; e < NEXP; ++e) {
        int start = off[e] + cnt[e];
        int end = off[e] + tiles[e] * TILE;
        for (int i = start + tid; i < end; i += 256) {
            tok_idx[i] = 0;
            tok_w[i] = 0.f;
        }
    }
}

// ---------------- fill token lists ----------------
__global__ __launch_bounds__(256) void k_fill(const int* __restrict__ top_idx,
                                              const float* __restrict__ top_w,
                                              Ctrl* __restrict__ ctrl,
                                              int* __restrict__ tok_idx,
                                              float* __restrict__ tok_w) {
    int n = blockIdx.x * 256 + threadIdx.x;
    if (n >= NTOK) return;
#pragma unroll
    for (int k = 0; k < 2; ++k) {
        int e = top_idx[n * 2 + k];
        int pos = atomicAdd(&ctrl->fill[e], 1);
        int slot = ctrl->padded_off[e] + pos;
        tok_idx[slot] = n;
        tok_w[slot] = top_w[n * 2 + k];
    }
}

// ======== 128x128, BK=64, SINGLE-buffer (m97 structure), 32 KB LDS, 4 blocks/CU ========
// (r16 structure — measured best: gemm2 264 us, MfmaUtil 22.5%, 0 conflicts.)
// r13 lesson: (256,4) is the reg-budget ceiling (acc 64 + frags 32 + addr ~25).
// Swizzle: stored chunk s at row holds global chunk s^(row&7); read chunk c ->
// stored c^(l15&7): 2 lanes/chunk-pair = 2-way bank alias (free, m136).
#define KLOOPM97(STA, STB, NK)                                                        \
    for (int kt = 0; kt < (NK); ++kt) {                                               \
        STA(kt); STB(kt);                                                             \
        asm volatile("s_waitcnt vmcnt(0)" ::: "memory");                              \
        __builtin_amdgcn_s_barrier();                                                 \
        bf16x8 a[4], b[4];                                                            \
        _Pragma("unroll") for (int m = 0; m < 4; ++m) a[m] = *(const bf16x8*)(sA + aoff[m] + csw0); \
        _Pragma("unroll") for (int n = 0; n < 4; ++n) b[n] = *(const bf16x8*)(sB + boff[n] + csw0); \
        __builtin_amdgcn_s_setprio(1);                                                \
        _Pragma("unroll") for (int m = 0; m < 4; ++m)                                 \
            _Pragma("unroll") for (int n = 0; n < 4; ++n)                             \
                acc[m][n] = __builtin_amdgcn_mfma_f32_16x16x32_bf16(a[m], b[n], acc[m][n], 0, 0, 0); \
        __builtin_amdgcn_s_setprio(0);                                                \
        _Pragma("unroll") for (int m = 0; m < 4; ++m) a[m] = *(const bf16x8*)(sA + aoff[m] + csw1); \
        _Pragma("unroll") for (int n = 0; n < 4; ++n) b[n] = *(const bf16x8*)(sB + boff[n] + csw1); \
        __builtin_amdgcn_s_setprio(1);                                                \
        _Pragma("unroll") for (int m = 0; m < 4; ++m)                                 \
            _Pragma("unroll") for (int n = 0; n < 4; ++n)                             \
                acc[m][n] = __builtin_amdgcn_mfma_f32_16x16x32_bf16(a[m], b[n], acc[m][n], 0, 0, 0); \
        __builtin_amdgcn_s_setprio(0);                                                \
        __builtin_amdgcn_s_barrier();                                                 \
    }

// ============ GEMM1: H = gelu(Xg @ w1^T + b1) [128x128, 4 blocks/CU] ============
__global__ __launch_bounds__(256, 4) void k_gemm1(const u16* __restrict__ xb,
                                                  const u16* __restrict__ w1b,
                                                  const float* __restrict__ b1,
                                                  const int* __restrict__ tok_idx,
                                                  const Ctrl* __restrict__ ctrl,
                                                  u16* __restrict__ H) {
    int flat = blockIdx.x;
    int t = (flat & 7) + ((flat >> 8) << 3);
    int n0 = ((flat >> 3) & 31) * TILE;
    if (t >= ctrl->n_tiles) return;
    int e = ctrl->tile_expert[t];
    int rbase = ctrl->tile_base[t];

    __shared__ __align__(16) u16 sA[REG64];
    __shared__ __align__(16) u16 sB[REG64];

    int tid = threadIdx.x;
    // 1024 16B units per matrix (128 rows x 8 chunks) -> 4 per thread
    const u16* aS[4];
    const u16* bS[4];
    int fo[4];
#pragma unroll
    for (int q = 0; q < 4; ++q) {
        int f = q * 256 + tid;                 // 0..1023
        int row = f >> 3;                      // 0..127
        int lc = (f & 7) ^ (row & 7);          // inverse-swizzled source chunk
        aS[q] = xb + (size_t)tok_idx[rbase + row] * DMODEL + lc * 8;
        bS[q] = w1b + (size_t)e * DFF * DMODEL + (size_t)(n0 + row) * DMODEL + lc * 8;
        fo[q] = f * 8;
    }

#define STA1(kt)                                                                      \
    do { _Pragma("unroll") for (int q = 0; q < 4; ++q)                                \
        load16(aS[q] + (kt) * 64, &sA[fo[q]]); } while (0)
#define STB1(kt)                                                                      \
    do { _Pragma("unroll") for (int q = 0; q < 4; ++q)                                \
        load16(bS[q] + (kt) * 64, &sB[fo[q]]); } while (0)

    int lane = tid & 63, w = tid >> 6;
    int wr = w >> 1, wc = w & 1;               // 2M x 2N waves; wave tile 64x64
    int l15 = lane & 15, lg = lane >> 4;
    int bank7 = l15 & 7;
    int csw0 = ((lg + 0) ^ bank7) * 8;         // kk0 chunk lg
    int csw1 = ((lg + 4) ^ bank7) * 8;         // kk1 chunk 4+lg

    int aoff[4], boff[4];
#pragma unroll
    for (int m = 0; m < 4; ++m) aoff[m] = (wr * 64 + m * 16 + l15) * 64;
#pragma unroll
    for (int n = 0; n < 4; ++n) boff[n] = (wc * 64 + n * 16 + l15) * 64;

    f32x4 acc[4][4];
#pragma unroll
    for (int m = 0; m < 4; ++m)
#pragma unroll
        for (int n = 0; n < 4; ++n) acc[m][n] = (f32x4){0.f, 0.f, 0.f, 0.f};

    KLOOPM97(STA1, STB1, DMODEL / 64)
#undef STA1
#undef STB1

    float bias[4];
#pragma unroll
    for (int n = 0; n < 4; ++n) bias[n] = b1[e * DFF + n0 + wc * 64 + n * 16 + l15];
#pragma unroll
    for (int m = 0; m < 4; ++m)
#pragma unroll
        for (int n = 0; n < 4; ++n) {
            int gcol = n0 + wc * 64 + n * 16 + l15;
#pragma unroll
            for (int r = 0; r < 4; ++r) {
                int grow = wr * 64 + m * 16 + lg * 4 + r;
                float h = acc[m][n][r] + bias[n];
                H[(size_t)(rbase + grow) * DFF + gcol] = f2bf(gelu_fast(h));
            }
        }
}

// ============ GEMM2: y += w * (H @ w2^T + b2) [128x128, 4 blocks/CU] ============
__global__ __launch_bounds__(256, 4) void k_gemm2(const u16* __restrict__ H,
                                                  const u16* __restrict__ w2b,
                                                  const float* __restrict__ b2,
                                                  const int* __restrict__ tok_idx,
                                                  const float* __restrict__ tok_w,
                                                  const Ctrl* __restrict__ ctrl,
                                                  float* __restrict__ y) {
    int flat = blockIdx.x;
    int t = (flat & 7) + ((flat >> 6) << 3);
    int n0 = ((flat >> 3) & 7) * TILE;
    if (t >= ctrl->n_tiles) return;
    int e = ctrl->tile_expert[t];
    int rbase = ctrl->tile_base[t];
    int valid = ctrl->tile_valid[t];

    __shared__ __align__(16) u16 sA[REG64];
    __shared__ __align__(16) u16 sB[REG64];

    int tid = threadIdx.x;
    const u16* aS[4];
    const u16* bS[4];
    int fo[4];
#pragma unroll
    for (int q = 0; q < 4; ++q) {
        int f = q * 256 + tid;
        int row = f >> 3;
        int lc = (f & 7) ^ (row & 7);
        aS[q] = H + (size_t)(rbase + row) * DFF + lc * 8;
        bS[q] = w2b + (size_t)e * DMODEL * DFF + (size_t)(n0 + row) * DFF + lc * 8;
        fo[q] = f * 8;
    }

#define STA2(kt)                                                                      \
    do { _Pragma("unroll") for (int q = 0; q < 4; ++q)                                \
        load16(aS[q] + (kt) * 64, &sA[fo[q]]); } while (0)
#define STB2(kt)                                                                      \
    do { _Pragma("unroll") for (int q = 0; q < 4; ++q)                                \
        load16(bS[q] + (kt) * 64, &sB[fo[q]]); } while (0)

    int lane = tid & 63, w = tid >> 6;
    int wr = w >> 1, wc = w & 1;
    int l15 = lane & 15, lg = lane >> 4;
    int bank7 = l15 & 7;
    int csw0 = ((lg + 0) ^ bank7) * 8;
    int csw1 = ((lg + 4) ^ bank7) * 8;

    int aoff[4], boff[4];
#pragma unroll
    for (int m = 0; m < 4; ++m) aoff[m] = (wr * 64 + m * 16 + l15) * 64;
#pragma unroll
    for (int n = 0; n < 4; ++n) boff[n] = (wc * 64 + n * 16 + l15) * 64;

    f32x4 acc[4][4];
#pragma unroll
    for (int m = 0; m < 4; ++m)
#pragma unroll
        for (int n = 0; n < 4; ++n) acc[m][n] = (f32x4){0.f, 0.f, 0.f, 0.f};

    KLOOPM97(STA2, STB2, DFF / 64)
#undef STA2
#undef STB2

    float bias[4];
#pragma unroll
    for (int n = 0; n < 4; ++n) bias[n] = b2[e * DMODEL + n0 + wc * 64 + n * 16 + l15];
#pragma unroll
    for (int m = 0; m < 4; ++m)
#pragma unroll
        for (int n = 0; n < 4; ++n) {
            int gcol = n0 + wc * 64 + n * 16 + l15;
#pragma unroll
            for (int r = 0; r < 4; ++r) {
                int grow = wr * 64 + m * 16 + lg * 4 + r;
                if (grow < valid) {
                    int slot = rbase + grow;
                    int tok = tok_idx[slot];
                    float wgt = tok_w[slot];
                    unsafeAtomicAdd(&y[(size_t)tok * DMODEL + gcol],
                                    wgt * (acc[m][n][r] + bias[n]));
                }
            }
        }
}

extern "C" void kernel_launch(void* const* d_in, const int* in_sizes, int n_in,
                              void* d_out, int out_size, void* d_ws, size_t ws_size,
                              hipStream_t stream) {
    (void)in_sizes; (void)n_in; (void)out_size; (void)ws_size;
    const float* x  = (const float*)d_in[0];
    const float* rw = (const float*)d_in[1];
    const float* w1 = (const float*)d_in[2];
    const float* b1 = (const float*)d_in[3];
    const float* w2 = (const float*)d_in[4];
    const float* b2 = (const float*)d_in[5];
    float* out = (float*)d_out;

    char* p = (char*)d_ws;
    Ctrl* ctrl = (Ctrl*)p;          p += 4096;
    u16* xb    = (u16*)p;           p += (size_t)NTOK * DMODEL * 2;
    u16* w1b   = (u16*)p;           p += (size_t)NEXP * DFF * DMODEL * 2;
    u16* w2b   = (u16*)p;           p += (size_t)NEXP * DMODEL * DFF * 2;
    u16* Hbuf  = (u16*)p;           p += (size_t)MAXROWS * DFF * 2;
    int* tok_idx = (int*)p;         p += (size_t)MAXROWS * 4;
    float* tok_w = (float*)p;       p += (size_t)MAXROWS * 4;
    int* tIdx  = (int*)p;           p += (size_t)NTOK * 2 * 4;
    float* tW  = (float*)p;         p += (size_t)NTOK * 2 * 4;

    hipMemsetAsync(ctrl, 0, sizeof(Ctrl), stream);
    hipMemsetAsync(d_out, 0, (size_t)NTOK * DMODEL * sizeof(float), stream);

    int n4a = NEXP * DFF * DMODEL / 4;
    k_convert2<<<2048, 256, 0, stream>>>(w1, w1b, n4a, w2, w2b, 2 * n4a);

    k_router<<<NTOK / 4, 256, 0, stream>>>(x, rw, xb, tIdx, tW, ctrl);
    k_build<<<1, 256, 0, stream>>>(tIdx, ctrl, tok_idx, tok_w, out);
    k_fill<<<NTOK / 256, 256, 0, stream>>>(tIdx, tW, ctrl, tok_idx, tok_w);

    // 1-D grids; (t, n0) derived in-kernel with XCD-chunked remap
    k_gemm1<<<MAXTILES * (DFF / TILE), 256, 0, stream>>>(xb, w1b, b1, tok_idx, ctrl, Hbuf);
    k_gemm2<<<MAXTILES * (DMODEL / TILE), 256, 0, stream>>>(Hbuf, w2b, b2, tok_idx, tok_w, ctrl, out);
}